// Round 14
// baseline (2256.910 us; speedup 1.0000x reference)
//
#include <hip/hip_runtime.h>

// ---------------------------------------------------------------------------
// VQ-VAE forward — all heavy conv layers on fp16 MFMA 16x16x32.
// Encoder (argmin-critical): 2-limb 3-product fp16 (validated r11-r13).
// Decoder: single-product fp16. c1a / t1a / t1b / recon fp32 vector.
// Round-14: (1) CO_F widened where LDS-capped occupancy makes staging the
// cost: c2a 4->8, c2b 4->8, c3a 2->4 (same arithmetic, bit-identical out).
// (2) LDS stride templated on NPROD: single-product kernels drop the unused
// lo-plane (144 -> 80 B/pixel, 57.9 -> 32 KB/block, 2 -> 5 blocks/CU).
// ---------------------------------------------------------------------------

using f32x4 = __attribute__((ext_vector_type(4))) float;
using f16x8 = __attribute__((ext_vector_type(8))) _Float16;  // 8 x fp16

__device__ __forceinline__ f32x4 mfma16(const f16x8& a, const f16x8& b, f32x4 c) {
    return __builtin_amdgcn_mfma_f32_16x16x32_f16(a, b, c, 0, 0, 0);
}

// tap tables: mode 0 = 25-tap s1 conv; 1..4 convT-s2 parities (flipped wi);
// 5..8 s2-conv parities (direct wi), (sy,sx)=(0,0),(0,1),(1,0),(1,1).
constexpr int MT_N[9] = {25, 9, 6, 6, 4, 9, 6, 6, 4};
constexpr int MT_DY[9][25] = {
  {-2,-2,-2,-2,-2,-1,-1,-1,-1,-1,0,0,0,0,0,1,1,1,1,1,2,2,2,2,2},
  {-2,-2,-2,-1,-1,-1, 0, 0, 0, 0,0,0,0,0,0,0,0,0,0,0,0,0,0,0,0},
  {-2,-2,-1,-1, 0, 0, 0, 0, 0, 0,0,0,0,0,0,0,0,0,0,0,0,0,0,0,0},
  {-1,-1,-1, 0, 0, 0, 0, 0, 0, 0,0,0,0,0,0,0,0,0,0,0,0,0,0,0,0},
  {-1,-1, 0, 0, 0, 0, 0, 0, 0, 0,0,0,0,0,0,0,0,0,0,0,0,0,0,0,0},
  { 0, 0, 0, 1, 1, 1, 2, 2, 2, 0,0,0,0,0,0,0,0,0,0,0,0,0,0,0,0},
  { 0, 0, 1, 1, 2, 2, 0, 0, 0, 0,0,0,0,0,0,0,0,0,0,0,0,0,0,0,0},
  { 0, 0, 0, 1, 1, 1, 0, 0, 0, 0,0,0,0,0,0,0,0,0,0,0,0,0,0,0,0},
  { 0, 0, 1, 1, 0, 0, 0, 0, 0, 0,0,0,0,0,0,0,0,0,0,0,0,0,0,0,0}};
constexpr int MT_DX[9][25] = {
  {-2,-1,0,1,2,-2,-1,0,1,2,-2,-1,0,1,2,-2,-1,0,1,2,-2,-1,0,1,2},
  {-2,-1, 0,-2,-1, 0,-2,-1, 0, 0,0,0,0,0,0,0,0,0,0,0,0,0,0,0,0},
  {-1, 0,-1, 0,-1, 0, 0, 0, 0, 0,0,0,0,0,0,0,0,0,0,0,0,0,0,0,0},
  {-2,-1, 0,-2,-1, 0, 0, 0, 0, 0,0,0,0,0,0,0,0,0,0,0,0,0,0,0,0},
  {-1, 0,-1, 0, 0, 0, 0, 0, 0, 0,0,0,0,0,0,0,0,0,0,0,0,0,0,0,0},
  { 0, 1, 2, 0, 1, 2, 0, 1, 2, 0,0,0,0,0,0,0,0,0,0,0,0,0,0,0,0},
  { 0, 1, 0, 1, 0, 1, 0, 0, 0, 0,0,0,0,0,0,0,0,0,0,0,0,0,0,0,0},
  { 0, 1, 2, 0, 1, 2, 0, 0, 0, 0,0,0,0,0,0,0,0,0,0,0,0,0,0,0,0},
  { 0, 1, 0, 1, 0, 0, 0, 0, 0, 0,0,0,0,0,0,0,0,0,0,0,0,0,0,0,0}};
constexpr int MT_WI[9][25] = {
  {0,1,2,3,4,5,6,7,8,9,10,11,12,13,14,15,16,17,18,19,20,21,22,23,24},
  {0, 2, 4,10,12,14,20,22,24, 0,0,0,0,0,0,0,0,0,0,0,0,0,0,0,0},
  {1, 3,11,13,21,23, 0, 0, 0, 0,0,0,0,0,0,0,0,0,0,0,0,0,0,0,0},
  {5, 7, 9,15,17,19, 0, 0, 0, 0,0,0,0,0,0,0,0,0,0,0,0,0,0,0,0},
  {6, 8,16,18, 0, 0, 0, 0, 0, 0,0,0,0,0,0,0,0,0,0,0,0,0,0,0,0},
  {0, 2, 4,10,12,14,20,22,24, 0,0,0,0,0,0,0,0,0,0,0,0,0,0,0,0},
  {1, 3,11,13,21,23, 0, 0, 0, 0,0,0,0,0,0,0,0,0,0,0,0,0,0,0,0},
  {5, 7, 9,15,17,19, 0, 0, 0, 0,0,0,0,0,0,0,0,0,0,0,0,0,0,0,0},
  {6, 8,16,18, 0, 0, 0, 0, 0, 0,0,0,0,0,0,0,0,0,0,0,0,0,0,0,0}};

// ---- ONE-SHOT weight prep (unchanged from r13) -----------------------------
__global__ __launch_bounds__(256) void pack_all(
    const float* __restrict__ t1a_w, const float* __restrict__ t1b_w,
    const float* __restrict__ t3b_w, const float* __restrict__ t2b_w,
    const float* __restrict__ t3a_w, const float* __restrict__ t2a_w,
    const float* __restrict__ c2a_w, const float* __restrict__ c3a_w,
    const float* __restrict__ c1b_w, const float* __restrict__ c2b_w,
    const float* __restrict__ c3b_w,
    float* __restrict__ wf, unsigned short* __restrict__ wpkb)
{
    constexpr int NJ = 26;
    constexpr int blk0[NJ + 1] =
        {0, 7, 8, 1608, 2008, 2296, 2488, 2680, 2808, 3096, 3288, 3480, 3608,
         4408, 5208, 5352, 5448, 5544, 5608, 6184, 6568, 6952, 7208,
         7352, 7448, 7544, 7608};
    constexpr int jkind[NJ] = {0,0,1,1,1,1,1,1,1,1,1,1,2,2, 2,2,2,2, 2,2,2,2, 2,2,2,2};
    constexpr int jmode[NJ] = {0,0,0,0,1,2,3,4,1,2,3,4,0,0, 5,6,7,8, 5,6,7,8, 5,6,7,8};
    constexpr int jci[NJ]   = {64,1,128,64,64,64,64,64,128,128,128,128,64,128,
                               64,64,64,64, 128,128,128,128, 64,64,64,64};
    constexpr int jco[NJ]   = {1,1,128,64,128,128,128,128,64,64,64,64,128,64,
                               64,64,64,64, 128,128,128,128, 64,64,64,64};
    constexpr int jsrc[NJ]  = {0,1,2,3,4,4,4,4,5,5,5,5,6,7, 8,8,8,8, 9,9,9,9, 10,10,10,10};
    constexpr long long jdst[NJ] = {921600,923200, 0,819200,
        1024000,1171456,1269760,1368064, 1433600,1581056,1679360,1777664,
        1843200, 2252800,
        2662400, 2736128, 2785280, 2834432,
        2867200, 3162112, 3358720, 3555328,
        3686400, 3760128, 3809280, 3858432};

    int b = blockIdx.x, j = 0;
#pragma unroll
    for (int k = 0; k < NJ; ++k) if (b >= blk0[k + 1]) j = k + 1;
    if (j >= NJ) return;
    const float* srcs[11] = {t1a_w, t1b_w, t3b_w, t2b_w, t3a_w, t2a_w,
                             c2a_w, c3a_w, c1b_w, c2b_w, c3b_w};
    const float* src = srcs[jsrc[j]];
    int idx = (b - blk0[j]) * 256 + (int)threadIdx.x;
    const int Ci = jci[j], Co = jco[j], mode = jmode[j];

    if (jkind[j] == 0) {
        int n = Ci * Co * 25;
        if (idx >= n) return;
        int t = idx % 25, rest = idx / 25;
        int ci = rest % Ci, co = rest / Ci;
        wf[jdst[j] + idx] = src[((size_t)ci * Co + co) * 25 + (24 - t)];
    } else {
        int NT = MT_N[mode];
        int nCB = Ci >> 5, nCoF = Co >> 4;
        int total = NT * nCB * nCoF * 512;
        if (idx >= total) return;
        int jj = idx & 7, lane = (idx >> 3) & 63;
        int rest = idx >> 9;
        int cof = rest % nCoF; int rest2 = rest / nCoF;
        int cb = rest2 % nCB;  int t = rest2 / nCB;
        int co = cof * 16 + (lane & 15);
        int ci = (cb << 5) + (lane >> 4) * 8 + jj;
        int wi = MT_WI[mode][t];
        float v = (jkind[j] == 1)
            ? src[((size_t)ci * Co + co) * 25 + (24 - wi)]   // flipped convT
            : src[((size_t)co * Ci + ci) * 25 + wi];         // direct conv
        _Float16 h = (_Float16)v;
        _Float16 l = (_Float16)(v - (float)h);
        unsigned short* dst = wpkb + jdst[j];
        size_t base = (size_t)rest * 1024;
        dst[base + lane * 8 + jj] = __builtin_bit_cast(unsigned short, h);
        dst[base + 512 + lane * 8 + jj] = __builtin_bit_cast(unsigned short, l);
    }
}

// LDS pixel stride: 2-limb needs 128B payload (+16 pad); single-limb 64 (+16).
template<int NPROD> struct lds_stride { static constexpr int v = 144; };
template<> struct lds_stride<1>       { static constexpr int v = 80;  };

// ---- tap compute (verified MFMA inner loop, fp16; NPROD 3=2-limb, 1=single)
template<int MODE, int CO_F, int NPROD>
__device__ __forceinline__ void mfma_taps(
    const char* s_x, const unsigned short* __restrict__ wpk,
    f32x4 (&acc)[4][CO_F], int lane, int wv, int px, int g,
    int cb, int nCB, int nCoF, int cof0)
{
    constexpr int NT = MT_N[MODE];
    constexpr int ST = lds_stride<NPROD>::v;
#pragma unroll
    for (int t = 0; t < NT; ++t) {
        const int dy = MT_DY[MODE][t], dx = MT_DX[MODE][t];
        f16x8 Bh[4], Bl[4];
#pragma unroll
        for (int rr = 0; rr < 4; ++rr) {
            int a = wv * 4 + rr;
            const char* p = &s_x[((a + dy + 2) * 20 + (dx + 2) + px) * ST + g * 16];
            Bh[rr] = *(const f16x8*)p;
            if constexpr (NPROD == 3) Bl[rr] = *(const f16x8*)(p + 64);
        }
#pragma unroll
        for (int cf = 0; cf < CO_F; ++cf) {
            const unsigned short* wp =
                wpk + ((size_t)(t * nCB + cb) * nCoF + (cof0 + cf)) * 1024 + (size_t)lane * 8;
            f16x8 Ah = *(const f16x8*)wp;
            if constexpr (NPROD == 3) {
                f16x8 Al = *(const f16x8*)(wp + 512);
#pragma unroll
                for (int rr = 0; rr < 4; ++rr) {
                    acc[rr][cf] = mfma16(Ah, Bh[rr], acc[rr][cf]);
                    acc[rr][cf] = mfma16(Ah, Bl[rr], acc[rr][cf]);
                    acc[rr][cf] = mfma16(Al, Bh[rr], acc[rr][cf]);
                }
            } else {
#pragma unroll
                for (int rr = 0; rr < 4; ++rr)
                    acc[rr][cf] = mfma16(Ah, Bh[rr], acc[rr][cf]);
            }
        }
    }
}

// staging: tile (ry,rx) -> orig (SS*(y0+ry-2)+sy, SS*(x0+rx-2)+sx); SS=1 or 2
template<int NPROD>
__device__ __forceinline__ void stage_tile(
    char* s_x, const float* __restrict__ inc, int tid,
    int y0, int x0, int SS, int sy, int sx, int Hin, int Win)
{
    constexpr int ST = lds_stride<NPROD>::v;
    for (int i = tid; i < 6400; i += 256) {
        int c2 = i / 400;
        int rem = i - c2 * 400;
        int ry = rem / 20, rx = rem - ry * 20;
        int y = SS * (y0 + ry - 2) + sy, x = SS * (x0 + rx - 2) + sx;
        float v0 = 0.f, v1 = 0.f;
        if ((unsigned)y < (unsigned)Hin && (unsigned)x < (unsigned)Win) {
            const float* p = inc + ((size_t)(c2 * 2) * Hin + y) * Win + x;
            v0 = p[0];
            v1 = p[(size_t)Hin * Win];
        }
        _Float16 h0 = (_Float16)v0, h1 = (_Float16)v1;
        char* base = &s_x[rem * ST + c2 * 4];
        *(unsigned*)(base) = (unsigned)__builtin_bit_cast(unsigned short, h0)
                           | ((unsigned)__builtin_bit_cast(unsigned short, h1) << 16);
        if constexpr (NPROD == 3) {
            _Float16 l0 = (_Float16)(v0 - (float)h0);
            _Float16 l1 = (_Float16)(v1 - (float)h1);
            *(unsigned*)(base + 64) = (unsigned)__builtin_bit_cast(unsigned short, l0)
                                    | ((unsigned)__builtin_bit_cast(unsigned short, l1) << 16);
        }
    }
}

// ---- stride-2 5x5 conv via 4-parity subplane MFMA (fp16 2-limb, encoder) ---
template<int CO_F>
__global__ __launch_bounds__(256) void conv_mfma_s2(
    const float* __restrict__ in,
    const unsigned short* __restrict__ w5, const unsigned short* __restrict__ w6,
    const unsigned short* __restrict__ w7, const unsigned short* __restrict__ w8,
    const float* __restrict__ bias, float* __restrict__ out,
    int Ci, int Co, int Hin, int Win, int Hout, int Wout, int nTX)
{
    __shared__ __align__(16) char s_x[400 * 144];
    const int tid = threadIdx.x;
    const int lane = tid & 63;
    const int wv = tid >> 6;
    const int px = lane & 15, g = lane >> 4;
    const int z = blockIdx.z;
    const int y0 = ((int)blockIdx.x / nTX) * 16;
    const int x0 = ((int)blockIdx.x % nTX) * 16;
    const int nCB = Ci >> 5;
    const int nCoF = Co >> 4;
    const int cof0 = (int)blockIdx.y * CO_F;
    const float* inz = in + (size_t)z * Ci * Hin * Win;

    f32x4 acc[4][CO_F];
#pragma unroll
    for (int rr = 0; rr < 4; ++rr)
#pragma unroll
        for (int cf = 0; cf < CO_F; ++cf) acc[rr][cf] = (f32x4){0.f, 0.f, 0.f, 0.f};

    for (int cb = 0; cb < nCB; ++cb) {
        const float* inc = inz + ((size_t)cb << 5) * Hin * Win;
        stage_tile<3>(s_x, inc, tid, y0, x0, 2, 0, 0, Hin, Win);
        __syncthreads();
        mfma_taps<5, CO_F, 3>(s_x, w5, acc, lane, wv, px, g, cb, nCB, nCoF, cof0);
        __syncthreads();
        stage_tile<3>(s_x, inc, tid, y0, x0, 2, 0, 1, Hin, Win);
        __syncthreads();
        mfma_taps<6, CO_F, 3>(s_x, w6, acc, lane, wv, px, g, cb, nCB, nCoF, cof0);
        __syncthreads();
        stage_tile<3>(s_x, inc, tid, y0, x0, 2, 1, 0, Hin, Win);
        __syncthreads();
        mfma_taps<7, CO_F, 3>(s_x, w7, acc, lane, wv, px, g, cb, nCB, nCoF, cof0);
        __syncthreads();
        stage_tile<3>(s_x, inc, tid, y0, x0, 2, 1, 1, Hin, Win);
        __syncthreads();
        mfma_taps<8, CO_F, 3>(s_x, w8, acc, lane, wv, px, g, cb, nCB, nCoF, cof0);
        __syncthreads();
    }
    const int ox = x0 + px;
    if (ox < Wout) {
#pragma unroll
        for (int rr = 0; rr < 4; ++rr) {
            int oy = y0 + wv * 4 + rr;
            if (oy < Hout) {
#pragma unroll
                for (int cf = 0; cf < CO_F; ++cf) {
                    int co = (cof0 + cf) * 16 + g * 4;
                    float* op = out + (((size_t)z * Co + co) * Hout + oy) * Wout + ox;
#pragma unroll
                    for (int i2 = 0; i2 < 4; ++i2) {
                        float v = acc[rr][cf][i2] + bias[co + i2];
                        op[(size_t)i2 * Hout * Wout] = v > 0.f ? v : 0.f;
                    }
                }
            }
        }
    }
}

// ---- MFMA conv body (s1 conv / convT parity; fp16, NPROD-templated) --------
template<int MODE, int CO_F, int NPROD>
__device__ __forceinline__ void conv_mfma_body(
    char* s_x,
    const float* __restrict__ in, const unsigned short* __restrict__ wpk,
    const float* __restrict__ bias, float* __restrict__ out,
    int Ci, int Co, int Hin, int Win, int Hout, int Wout,
    int nTX, int OS, int soy, int sox, int cofBlk)
{
    const int tid = threadIdx.x;
    const int lane = tid & 63;
    const int wv = tid >> 6;
    const int px = lane & 15, g = lane >> 4;
    const int z = blockIdx.z;
    const int y0 = ((int)blockIdx.x / nTX) * 16;
    const int x0 = ((int)blockIdx.x % nTX) * 16;
    const int nCB = Ci >> 5;
    const int nCoF = Co >> 4;
    const int cof0 = cofBlk * CO_F;
    const float* inz = in + (size_t)z * Ci * Hin * Win;

    f32x4 acc[4][CO_F];
#pragma unroll
    for (int rr = 0; rr < 4; ++rr)
#pragma unroll
        for (int cf = 0; cf < CO_F; ++cf) acc[rr][cf] = (f32x4){0.f, 0.f, 0.f, 0.f};

    for (int cb = 0; cb < nCB; ++cb) {
        const float* inc = inz + ((size_t)cb << 5) * Hin * Win;
        stage_tile<NPROD>(s_x, inc, tid, y0, x0, 1, 0, 0, Hin, Win);
        __syncthreads();
        mfma_taps<MODE, CO_F, NPROD>(s_x, wpk, acc, lane, wv, px, g, cb, nCB, nCoF, cof0);
        __syncthreads();
    }
    const int ox = (x0 + px) * OS + sox;
    if (ox < Wout) {
#pragma unroll
        for (int rr = 0; rr < 4; ++rr) {
            int oy = (y0 + wv * 4 + rr) * OS + soy;
            if (oy < Hout) {
#pragma unroll
                for (int cf = 0; cf < CO_F; ++cf) {
                    int co = (cof0 + cf) * 16 + g * 4;
                    float* op = out + (((size_t)z * Co + co) * Hout + oy) * Wout + ox;
#pragma unroll
                    for (int i2 = 0; i2 < 4; ++i2) {
                        float v = acc[rr][cf][i2] + bias[co + i2];
                        op[(size_t)i2 * Hout * Wout] = v > 0.f ? v : 0.f;
                    }
                }
            }
        }
    }
}

// s1-conv launches (mode 0)
template<int MODE, int CO_F, int NPROD = 3>
__global__ __launch_bounds__(256) void conv_mfma(
    const float* __restrict__ in, const unsigned short* __restrict__ wpk,
    const float* __restrict__ bias, float* __restrict__ out,
    int Ci, int Co, int Hin, int Win, int Hout, int Wout,
    int nTX, int OS, int soy, int sox)
{
    __shared__ __align__(16) char s_x[400 * lds_stride<NPROD>::v];
    conv_mfma_body<MODE, CO_F, NPROD>(s_x, in, wpk, bias, out, Ci, Co, Hin, Win,
                                      Hout, Wout, nTX, OS, soy, sox, (int)blockIdx.y);
}

// merged 4-parity convT (decoder, fp16 single-product, 32KB LDS)
template<int CO_F>
__global__ __launch_bounds__(256) void convt_mfma_all(
    const float* __restrict__ in,
    const unsigned short* __restrict__ w1, const unsigned short* __restrict__ w2,
    const unsigned short* __restrict__ w3, const unsigned short* __restrict__ w4,
    const float* __restrict__ bias, float* __restrict__ out,
    int Ci, int Co, int Hin, int Win, int Hout, int Wout, int nTX, int cofN)
{
    __shared__ __align__(16) char s_x[400 * lds_stride<1>::v];
    int m = (int)blockIdx.y / cofN;
    int yy = (int)blockIdx.y % cofN;
    if (m == 0)
        conv_mfma_body<1, CO_F, 1>(s_x, in, w1, bias, out, Ci, Co, Hin, Win, Hout, Wout, nTX, 2, 0, 0, yy);
    else if (m == 1)
        conv_mfma_body<2, CO_F, 1>(s_x, in, w2, bias, out, Ci, Co, Hin, Win, Hout, Wout, nTX, 2, 0, 1, yy);
    else if (m == 2)
        conv_mfma_body<3, CO_F, 1>(s_x, in, w3, bias, out, Ci, Co, Hin, Win, Hout, Wout, nTX, 2, 1, 0, yy);
    else
        conv_mfma_body<4, CO_F, 1>(s_x, in, w4, bias, out, Ci, Co, Hin, Win, Hout, Wout, nTX, 2, 1, 1, yy);
}

// ---- c1a: 1->64 s1p2 on 256x256, all 64 co per block (proven) -------------
__global__ __launch_bounds__(256, 4) void conv_c1a(
    const float* __restrict__ in, const float* __restrict__ w,  // w (64,25)
    const float* __restrict__ bias, float* __restrict__ out)
{
    __shared__ float s_in[36 * 36];
    const int z = blockIdx.z;
    const float* inz = in + (size_t)z * 65536;
    float* outz = out + (size_t)z * 64 * 65536;
    const int ty0 = ((int)blockIdx.x >> 3) * 32;
    const int tx0 = ((int)blockIdx.x & 7) * 32;
    const int tid = threadIdx.x;
    const int r  = tid >> 3;
    const int c4 = (tid & 7) * 4;
    const int iy0 = ty0 - 2, ix0 = tx0 - 2;

    for (int i = tid; i < 36 * 36; i += 256) {
        int rr = i / 36, cc = i - rr * 36;
        int y = iy0 + rr, x = ix0 + cc;
        float v = 0.f;
        if ((unsigned)y < 256u && (unsigned)x < 256u) v = inz[y * 256 + x];
        s_in[i] = v;
    }
    __syncthreads();

    float win[5][8];
#pragma unroll
    for (int ky = 0; ky < 5; ++ky) {
        const float* rowp = &s_in[(r + ky) * 36 + c4];
        float4 a = *(const float4*)rowp;
        float4 b = *(const float4*)(rowp + 4);
        win[ky][0]=a.x; win[ky][1]=a.y; win[ky][2]=a.z; win[ky][3]=a.w;
        win[ky][4]=b.x; win[ky][5]=b.y; win[ky][6]=b.z; win[ky][7]=b.w;
    }

    float* obase = outz + (size_t)(ty0 + r) * 256 + tx0 + c4;
    for (int j0 = 0; j0 < 64; j0 += 8) {
#pragma unroll
        for (int j = 0; j < 8; ++j) {
            const int co = j0 + j;
            const float* wj = w + co * 25;
            float a0 = 0.f, a1 = 0.f, a2 = 0.f, a3 = 0.f;
#pragma unroll
            for (int ky = 0; ky < 5; ++ky)
#pragma unroll
                for (int kx = 0; kx < 5; ++kx) {
                    float wv = wj[ky * 5 + kx];
                    a0 = fmaf(win[ky][kx],     wv, a0);
                    a1 = fmaf(win[ky][kx + 1], wv, a1);
                    a2 = fmaf(win[ky][kx + 2], wv, a2);
                    a3 = fmaf(win[ky][kx + 3], wv, a3);
                }
            float bv = bias[co];
            float4 v;
            v.x = a0 + bv; v.y = a1 + bv; v.z = a2 + bv; v.w = a3 + bv;
            v.x = v.x > 0.f ? v.x : 0.f;  v.y = v.y > 0.f ? v.y : 0.f;
            v.z = v.z > 0.f ? v.z : 0.f;  v.w = v.w > 0.f ? v.w : 0.f;
            *(float4*)(obase + (size_t)co * 65536) = v;
        }
    }
}

// ---- stride-1 5x5 conv (fp32), proven body (recon only) -------------------
template<int CO_PER>
__global__ __launch_bounds__(256) void conv5x5_s1(
    const float* __restrict__ in, const float* __restrict__ w,   // w (Co,Ci,25)
    const float* __restrict__ bias, float* __restrict__ out,
    int Ci, int Co, int Hin, int Win, int Hout, int Wout, int nTX)
{
    __shared__ float s_in[2][36 * 36];
    const int z = blockIdx.z;
    const float* inz = in + (size_t)z * Ci * Hin * Win;
    float* outz = out + (size_t)z * Co * Hout * Wout;
    const int co0 = blockIdx.y * CO_PER;
    const int ty0 = ((int)blockIdx.x / nTX) * 32;
    const int tx0 = ((int)blockIdx.x % nTX) * 32;
    const int tid = threadIdx.x;
    const int r  = tid >> 3;
    const int c4 = (tid & 7) * 4;
    const int oy = ty0 + r;
    const int ox0 = tx0 + c4;
    const int iy0 = ty0 - 2, ix0 = tx0 - 2;

    float acc[CO_PER][4];
#pragma unroll
    for (int j = 0; j < CO_PER; ++j)
#pragma unroll
        for (int p = 0; p < 4; ++p) acc[j][p] = 0.f;

    for (int ci0 = 0; ci0 < Ci; ci0 += 2) {
        const int nci = (Ci - ci0 >= 2) ? 2 : 1;
        for (int s = 0; s < nci; ++s) {
            const float* inc = inz + (size_t)(ci0 + s) * Hin * Win;
            for (int i = tid; i < 36 * 36; i += 256) {
                int rr = i / 36, cc = i - rr * 36;
                int y = iy0 + rr, x = ix0 + cc;
                float v = 0.f;
                if ((unsigned)y < (unsigned)Hin && (unsigned)x < (unsigned)Win)
                    v = inc[y * Win + x];
                s_in[s][i] = v;
            }
        }
        __syncthreads();
        for (int s = 0; s < nci; ++s) {
            const float* wc = w + (co0 * Ci + ci0 + s) * 25;
            float win[5][8];
#pragma unroll
            for (int ky = 0; ky < 5; ++ky) {
                const float* rowp = &s_in[s][(r + ky) * 36 + c4];
                float4 a = *(const float4*)rowp;
                float4 b = *(const float4*)(rowp + 4);
                win[ky][0]=a.x; win[ky][1]=a.y; win[ky][2]=a.z; win[ky][3]=a.w;
                win[ky][4]=b.x; win[ky][5]=b.y; win[ky][6]=b.z; win[ky][7]=b.w;
            }
#pragma unroll
            for (int j = 0; j < CO_PER; ++j) {
#pragma unroll
                for (int ky = 0; ky < 5; ++ky) {
#pragma unroll
                    for (int kx = 0; kx < 5; ++kx) {
                        float wv = wc[j * Ci * 25 + ky * 5 + kx];
#pragma unroll
                        for (int p = 0; p < 4; ++p)
                            acc[j][p] = fmaf(win[ky][p + kx], wv, acc[j][p]);
                    }
                }
            }
        }
        __syncthreads();
    }
    if (oy < Hout) {
#pragma unroll
        for (int j = 0; j < CO_PER; ++j) {
            const int co = co0 + j;
            const float bv = bias[co];
            float* orow = outz + (size_t)co * Hout * Wout + (size_t)oy * Wout;
#pragma unroll
            for (int p = 0; p < 4; ++p) {
                int ox = ox0 + p;
                if (ox < Wout) {
                    float v = acc[j][p] + bv;
                    orow[ox] = v > 0.f ? v : 0.f;
                }
            }
        }
    }
}

// ---- ConvTranspose2d stride=2 quad gather (fp32; t1a only) ----------------
template<int CO_PER>
__global__ __launch_bounds__(256) void convt5x5_quad(
    const float* __restrict__ in, const float* __restrict__ w,  // flipped (Co,Ci,25)
    const float* __restrict__ bias, float* __restrict__ out,
    int Ci, int Co, int Hin, int Win, int Hout, int Wout, int nTX)
{
    __shared__ float s_in[2][18 * 20];
    const int z = blockIdx.z;
    const float* inz = in + (size_t)z * Ci * Hin * Win;
    float* outz = out + (size_t)z * Co * Hout * Wout;
    const int co0 = blockIdx.y * CO_PER;
    const int a0 = ((int)blockIdx.x / nTX) * 16;
    const int b0 = ((int)blockIdx.x % nTX) * 16;
    const int tid = threadIdx.x;
    const int r = tid >> 4, c = tid & 15;

    float acc[CO_PER][4];
#pragma unroll
    for (int j = 0; j < CO_PER; ++j)
#pragma unroll
        for (int p = 0; p < 4; ++p) acc[j][p] = 0.f;

    for (int ci0 = 0; ci0 < Ci; ci0 += 2) {
        const int nci = (Ci - ci0 >= 2) ? 2 : 1;
        for (int s = 0; s < nci; ++s) {
            const float* inc = inz + (size_t)(ci0 + s) * Hin * Win;
            for (int i = tid; i < 18 * 18; i += 256) {
                int rr = i / 18, cc = i - rr * 18;
                int y = a0 - 2 + rr, x = b0 - 2 + cc;
                float v = 0.f;
                if (y >= 0 && y < Hin && x >= 0 && x < Win) v = inc[y * Win + x];
                s_in[s][rr * 20 + cc] = v;
            }
        }
        __syncthreads();
        for (int s = 0; s < nci; ++s) {
            const float* wc = w + (co0 * Ci + ci0 + s) * 25;
            float v[3][3];
#pragma unroll
            for (int i = 0; i < 3; ++i)
#pragma unroll
                for (int jx = 0; jx < 3; ++jx)
                    v[i][jx] = s_in[s][(r + i) * 20 + c + jx];
#pragma unroll
            for (int j = 0; j < CO_PER; ++j) {
                const float* wj = wc + j * Ci * 25;
#pragma unroll
                for (int ty = 0; ty < 3; ++ty)
#pragma unroll
                    for (int tx = 0; tx < 3; ++tx)
                        acc[j][0] = fmaf(v[ty][tx], wj[2*ty*5 + 2*tx], acc[j][0]);
#pragma unroll
                for (int ty = 0; ty < 3; ++ty)
#pragma unroll
                    for (int tx = 0; tx < 2; ++tx)
                        acc[j][1] = fmaf(v[ty][tx+1], wj[2*ty*5 + 2*tx+1], acc[j][1]);
#pragma unroll
                for (int ty = 0; ty < 2; ++ty)
#pragma unroll
                    for (int tx = 0; tx < 3; ++tx)
                        acc[j][2] = fmaf(v[ty+1][tx], wj[(2*ty+1)*5 + 2*tx], acc[j][2]);
#pragma unroll
                for (int ty = 0; ty < 2; ++ty)
#pragma unroll
                    for (int tx = 0; tx < 2; ++tx)
                        acc[j][3] = fmaf(v[ty+1][tx+1], wj[(2*ty+1)*5 + 2*tx+1], acc[j][3]);
            }
        }
        __syncthreads();
    }
    const int a = a0 + r, bq = b0 + c;
#pragma unroll
    for (int j = 0; j < CO_PER; ++j) {
        const int co = co0 + j;
        const float bv = bias[co];
        float* oc = outz + (size_t)co * Hout * Wout;
#pragma unroll
        for (int sy = 0; sy < 2; ++sy) {
            int oy = 2 * a + sy;
            if (oy < Hout) {
#pragma unroll
                for (int sx = 0; sx < 2; ++sx) {
                    int ox = 2 * bq + sx;
                    if (ox < Wout) {
                        float vv = acc[j][sy * 2 + sx] + bv;
                        oc[(size_t)oy * Wout + ox] = vv > 0.f ? vv : 0.f;
                    }
                }
            }
        }
    }
}

// VQ: argmin_k( ||e_k||^2 - 2 z.e_k ), float4 over k; strict < == first-min.
__global__ __launch_bounds__(256, 4) void vq_kernel(
    const float* __restrict__ before, const float* __restrict__ e,
    float* __restrict__ idxs_out, float* __restrict__ after,
    int npos, int HW)
{
    __shared__ float s_e[64 * 128];
    __shared__ float s_n[128];
    for (int i = threadIdx.x; i < 64 * 128; i += 256) s_e[i] = e[i];
    __syncthreads();
    if (threadIdx.x < 128) {
        int k = threadIdx.x;
        float s = 0.f;
#pragma unroll
        for (int d = 0; d < 64; ++d) { float v = s_e[d * 128 + k]; s += v * v; }
        s_n[k] = s;
    }
    __syncthreads();

    int p = blockIdx.x * 256 + threadIdx.x;
    if (p >= npos) return;
    int b = p / HW, r = p - b * HW;

    float zv[64];
#pragma unroll
    for (int d = 0; d < 64; ++d)
        zv[d] = before[((size_t)b * 64 + d) * HW + r];

    float best = 1e30f;
    int bi = 0;
    for (int k0 = 0; k0 < 128; k0 += 4) {
        float d0 = 0.f, d1 = 0.f, d2 = 0.f, d3 = 0.f;
#pragma unroll
        for (int d = 0; d < 64; ++d) {
            float4 ev = *(const float4*)&s_e[d * 128 + k0];
            d0 = fmaf(zv[d], ev.x, d0);
            d1 = fmaf(zv[d], ev.y, d1);
            d2 = fmaf(zv[d], ev.z, d2);
            d3 = fmaf(zv[d], ev.w, d3);
        }
        float m0 = s_n[k0]     - 2.f * d0;
        float m1 = s_n[k0 + 1] - 2.f * d1;
        float m2 = s_n[k0 + 2] - 2.f * d2;
        float m3 = s_n[k0 + 3] - 2.f * d3;
        if (m0 < best) { best = m0; bi = k0; }
        if (m1 < best) { best = m1; bi = k0 + 1; }
        if (m2 < best) { best = m2; bi = k0 + 2; }
        if (m3 < best) { best = m3; bi = k0 + 3; }
    }
    idxs_out[p] = (float)bi;
#pragma unroll
    for (int d = 0; d < 64; ++d)
        after[((size_t)b * 64 + d) * HW + r] = s_e[d * 128 + bi];
}

extern "C" void kernel_launch(void* const* d_in, const int* in_sizes, int n_in,
                              void* d_out, int out_size, void* d_ws, size_t ws_size,
                              hipStream_t stream)
{
    const float* x     = (const float*)d_in[0];
    const float* e     = (const float*)d_in[1];
    const float* c1a_w = (const float*)d_in[2];  const float* c1a_b = (const float*)d_in[3];
    const float* c1b_w = (const float*)d_in[4];  const float* c1b_b = (const float*)d_in[5];
    const float* c2a_w = (const float*)d_in[6];  const float* c2a_b = (const float*)d_in[7];
    const float* c2b_w = (const float*)d_in[8];  const float* c2b_b = (const float*)d_in[9];
    const float* c3a_w = (const float*)d_in[10]; const float* c3a_b = (const float*)d_in[11];
    const float* c3b_w = (const float*)d_in[12]; const float* c3b_b = (const float*)d_in[13];
    const float* t3a_w = (const float*)d_in[14]; const float* t3a_b = (const float*)d_in[15];
    const float* t3b_w = (const float*)d_in[16]; const float* t3b_b = (const float*)d_in[17];
    const float* t2a_w = (const float*)d_in[18]; const float* t2a_b = (const float*)d_in[19];
    const float* t2b_w = (const float*)d_in[20]; const float* t2b_b = (const float*)d_in[21];
    const float* t1a_w = (const float*)d_in[22]; const float* t1a_b = (const float*)d_in[23];
    const float* t1b_w = (const float*)d_in[24]; const float* t1b_b = (const float*)d_in[25];

    float* out = (float*)d_out;
    float* ws  = (float*)d_ws;

    // d_out layout: recon | idxs | before | after
    float* o_recon  = out;                // 16*253*253 = 1,024,144
    float* o_idxs   = out + 1024144;     // 16*29*29   = 13,456
    float* o_before = out + 1037600;     // 16*64*29*29= 861,184
    float* o_after  = out + 1898784;     // 861,184

    // --- exact tensor sizes (floats) ---
    constexpr size_t S_H1F  = (size_t)16 * 64 * 256 * 256;   // 67,108,864
    constexpr size_t S_H1G  = (size_t)8  * 64 * 256 * 256;   // 33,554,432
    constexpr size_t S126x64  = (size_t)16 * 64  * 126 * 126; // 16,257,024
    constexpr size_t S126x128 = (size_t)16 * 128 * 126 * 126; // 32,514,048
    constexpr size_t S61x128  = (size_t)16 * 128 * 61 * 61;   // 7,620,608
    constexpr size_t S61x64   = (size_t)16 * 64  * 61 * 61;   // 3,810,304
    constexpr size_t S125x64  = (size_t)16 * 64  * 125 * 125; // 16,000,000
    constexpr size_t S253     = (size_t)16 * 253 * 253;       // 1,024,144
    constexpr size_t S_WF     = 923232;    // flipped t1a/t1b weights region
    constexpr size_t S_WPK    = 1945600;   // MFMA packs: 3,891,200 ushorts

    // ---- full-batch plan ----
    constexpr size_t F_h1 = 0;
    constexpr size_t F_h2 = F_h1 + S_H1F;            // 67,108,864
    constexpr size_t F_h3 = 0;
    constexpr size_t F_h4 = F_h3 + S126x128;         // 32,514,048
    constexpr size_t F_h5 = F_h4 + S61x128;          // 40,134,656
    constexpr size_t F_wf = F_h2 + S126x64;          // 83,365,888
    constexpr size_t F_wk = F_wf + S_WF;             // 84,289,120
    constexpr size_t F_r1 = F_h5 + S61x64;           // 43,944,960
    constexpr size_t F_r2 = F_r1 + S61x128;          // 51,565,568
    constexpr size_t F_r3 = 0;
    constexpr size_t F_r4 = F_r3 + S125x64;          // 16,000,000
    constexpr size_t F_r5 = F_r2 + S61x128;          // 59,186,176
    constexpr size_t FULL_NEED = F_wk + S_WPK;       // 86,234,720

    // ---- 8-image-group fallback plan (the plan actually in use) ----
    constexpr size_t G_h1 = 0;
    constexpr size_t G_h2 = G_h1 + S_H1G;            // 33,554,432
    constexpr size_t G_h3 = 0;
    constexpr size_t G_h4 = G_h2;                    // overwrites dead h2
    constexpr size_t G_h5 = G_h4 + S61x128;          // 41,175,040
    constexpr size_t G_wf = G_h2 + S126x64;          // 49,811,456
    constexpr size_t G_wk = G_wf + S_WF;             // 50,734,688
    constexpr size_t G_r1 = 0;
    constexpr size_t G_r2 = G_r1 + S61x128;          // 7,620,608
    constexpr size_t G_r3 = G_r2 + S61x128;          // 15,241,216
    constexpr size_t G_r4 = G_r3 + S125x64;          // 31,241,216
    constexpr size_t G_r5 = G_r4 + S125x64;          // 47,241,216
    constexpr size_t G8_NEED = G_wk + S_WPK;         // 52,680,288

    static_assert(F_r5 + S253 <= F_h2, "F r5 under h2");
    static_assert(G_r5 + S253 <= G_wf, "g8 r5/wf");
    static_assert(G_h5 + S61x64 <= G_wf, "g8 h5/wf");

    if (ws_size < G8_NEED * sizeof(float)) return;
    const bool full = ws_size >= FULL_NEED * sizeof(float);

    float *h1, *h2, *h3, *h4, *h5, *wf, *r1, *r2, *r3, *r4, *r5;
    unsigned short* wpkb;
    if (full) {
        h1 = ws + F_h1; h2 = ws + F_h2; h3 = ws + F_h3; h4 = ws + F_h4;
        h5 = ws + F_h5; wf = ws + F_wf; r1 = ws + F_r1; r2 = ws + F_r2;
        r3 = ws + F_r3; r4 = ws + F_r4; r5 = ws + F_r5;
        wpkb = (unsigned short*)(ws + F_wk);
    } else {
        h1 = ws + G_h1; h2 = ws + G_h2; h3 = ws + G_h3; h4 = ws + G_h4;
        h5 = ws + G_h5; wf = ws + G_wf; r1 = ws + G_r1; r2 = ws + G_r2;
        r3 = ws + G_r3; r4 = ws + G_r4; r5 = ws + G_r5;
        wpkb = (unsigned short*)(ws + G_wk);
    }
    float* wf_t1a = wf + 921600;     // 1*64*25 = 1,600
    float* wf_t1b = wf + 923200;     // 25
    unsigned short* wpk_t3b = wpkb;                 // 819,200
    unsigned short* wpk_t2b = wpkb + 819200;        // 204,800
    unsigned short* wpk_t3a[4] = {wpkb + 1024000, wpkb + 1171456, wpkb + 1269760, wpkb + 1368064};
    unsigned short* wpk_t2a[4] = {wpkb + 1433600, wpkb + 1581056, wpkb + 1679360, wpkb + 1777664};
    unsigned short* wpk_c2a = wpkb + 1843200;       // 409,600 (fp16 direct)
    unsigned short* wpk_c3a = wpkb + 2252800;       // 409,600 (fp16 direct)
    unsigned short* wpk_c1b[4] = {wpkb + 2662400, wpkb + 2736128, wpkb + 2785280, wpkb + 2834432};
    unsigned short* wpk_c2b[4] = {wpkb + 2867200, wpkb + 3162112, wpkb + 3358720, wpkb + 3555328};
    unsigned short* wpk_c3b[4] = {wpkb + 3686400, wpkb + 3760128, wpkb + 3809280, wpkb + 3858432};

    // --- weight prep: single fused launch ---
    pack_all<<<dim3(7608), 256, 0, stream>>>(
        t1a_w, t1b_w, t3b_w, t2b_w, t3a_w, t2a_w, c2a_w, c3a_w,
        c1b_w, c2b_w, c3b_w, wf, wpkb);

    // --- encoder (3-product fp16; idxs-exact path, validated r11-r13) ---
    if (full) {
        conv_c1a<<<dim3(64, 1, 16), 256, 0, stream>>>(x, c1a_w, c1a_b, h1);
        conv_mfma_s2<4><<<dim3(64, 1, 16), 256, 0, stream>>>(
            h1, wpk_c1b[0], wpk_c1b[1], wpk_c1b[2], wpk_c1b[3],
            c1b_b, h2, 64, 64, 256, 256, 126, 126, 8);
    } else {
        for (int g = 0; g < 2; ++g) {
            conv_c1a<<<dim3(64, 1, 8), 256, 0, stream>>>(
                x + (size_t)g * 8 * 65536, c1a_w, c1a_b, h1);
            conv_mfma_s2<4><<<dim3(64, 1, 8), 256, 0, stream>>>(
                h1, wpk_c1b[0], wpk_c1b[1], wpk_c1b[2], wpk_c1b[3],
                c1b_b, h2 + (size_t)g * 8 * 64 * 126 * 126,
                64, 64, 256, 256, 126, 126, 8);
        }
    }
    // c2a: CO_F=8 (all 128 co per block; halves staging per output)
    conv_mfma<0, 8, 3><<<dim3(64, 1, 16), 256, 0, stream>>>(
        h2, wpk_c2a, c2a_b, h3, 64, 128, 126, 126, 126, 126, 8, 1, 0, 0);
    // c2b: CO_F=8
    conv_mfma_s2<8><<<dim3(16, 1, 16), 256, 0, stream>>>(
        h3, wpk_c2b[0], wpk_c2b[1], wpk_c2b[2], wpk_c2b[3],
        c2b_b, h4, 128, 128, 126, 126, 61, 61, 4);
    // c3a: CO_F=4
    conv_mfma<0, 4, 3><<<dim3(16, 1, 16), 256, 0, stream>>>(
        h4, wpk_c3a, c3a_b, h5, 128, 64, 61, 61, 61, 61, 4, 1, 0, 0);
    conv_mfma_s2<4><<<dim3(4, 1, 16), 256, 0, stream>>>(
        h5, wpk_c3b[0], wpk_c3b[1], wpk_c3b[2], wpk_c3b[3],
        c3b_b, o_before, 64, 64, 61, 61, 29, 29, 2);

    // --- VQ ---
    vq_kernel<<<dim3(53), 256, 0, stream>>>(o_before, e, o_idxs, o_after, 13456, 841);

    // --- decoder (single-product fp16, 32KB LDS); fp32 for t1a/t1b ---
    convt_mfma_all<4><<<dim3(4, 8, 16), 256, 0, stream>>>(
        o_after, wpk_t3a[0], wpk_t3a[1], wpk_t3a[2], wpk_t3a[3],
        t3a_b, r1, 64, 128, 29, 29, 61, 61, 2, 2);                    // t3a
    conv_mfma<0, 4, 1><<<dim3(16, 2, 16), 256, 0, stream>>>(
        r1, wpk_t3b, t3b_b, r2, 128, 128, 61, 61, 61, 61, 4, 1, 0, 0); // t3b
    convt_mfma_all<4><<<dim3(16, 4, 16), 256, 0, stream>>>(
        r2, wpk_t2a[0], wpk_t2a[1], wpk_t2a[2], wpk_t2a[3],
        t2a_b, r3, 128, 64, 61, 61, 125, 125, 4, 1);                   // t2a
    conv_mfma<0, 4, 1><<<dim3(64, 1, 16), 256, 0, stream>>>(
        r3, wpk_t2b, t2b_b, r4, 64, 64, 125, 125, 125, 125, 8, 1, 0, 0); // t2b
    convt5x5_quad<1><<<dim3(64, 1, 16), 256, 0, stream>>>(
        r4, wf_t1a, t1a_b, r5, 64, 1, 125, 125, 253, 253, 8);          // t1a
    conv5x5_s1<1><<<dim3(64, 1, 16), 256, 0, stream>>>(
        r5, wf_t1b, t1b_b, o_recon, 1, 1, 253, 253, 253, 253, 8);      // recon
}

// Round 15
// 1795.791 us; speedup vs baseline: 1.2568x; 1.2568x over previous
//
#include <hip/hip_runtime.h>

// ---------------------------------------------------------------------------
// VQ-VAE forward — all heavy conv layers on fp16 MFMA 16x16x32.
// Encoder (argmin-critical): 2-limb 3-product fp16 (validated r11-r14).
// Decoder: single-product fp16. c1a / t1a / t1b / recon fp32 vector.
// Round-15: unbundle r14 — revert CO_F widening (r14: VGPR 124->156 crossed
// the occupancy cliff, c2a 336->585us); keep ONLY the NPROD-templated LDS
// stride (decoder 57.9->32KB/block, no register cost). Launch geometry is
// byte-identical to round 13 (1,798us proven).
// ---------------------------------------------------------------------------

using f32x4 = __attribute__((ext_vector_type(4))) float;
using f16x8 = __attribute__((ext_vector_type(8))) _Float16;  // 8 x fp16

__device__ __forceinline__ f32x4 mfma16(const f16x8& a, const f16x8& b, f32x4 c) {
    return __builtin_amdgcn_mfma_f32_16x16x32_f16(a, b, c, 0, 0, 0);
}

// tap tables: mode 0 = 25-tap s1 conv; 1..4 convT-s2 parities (flipped wi);
// 5..8 s2-conv parities (direct wi), (sy,sx)=(0,0),(0,1),(1,0),(1,1).
constexpr int MT_N[9] = {25, 9, 6, 6, 4, 9, 6, 6, 4};
constexpr int MT_DY[9][25] = {
  {-2,-2,-2,-2,-2,-1,-1,-1,-1,-1,0,0,0,0,0,1,1,1,1,1,2,2,2,2,2},
  {-2,-2,-2,-1,-1,-1, 0, 0, 0, 0,0,0,0,0,0,0,0,0,0,0,0,0,0,0,0},
  {-2,-2,-1,-1, 0, 0, 0, 0, 0, 0,0,0,0,0,0,0,0,0,0,0,0,0,0,0,0},
  {-1,-1,-1, 0, 0, 0, 0, 0, 0, 0,0,0,0,0,0,0,0,0,0,0,0,0,0,0,0},
  {-1,-1, 0, 0, 0, 0, 0, 0, 0, 0,0,0,0,0,0,0,0,0,0,0,0,0,0,0,0},
  { 0, 0, 0, 1, 1, 1, 2, 2, 2, 0,0,0,0,0,0,0,0,0,0,0,0,0,0,0,0},
  { 0, 0, 1, 1, 2, 2, 0, 0, 0, 0,0,0,0,0,0,0,0,0,0,0,0,0,0,0,0},
  { 0, 0, 0, 1, 1, 1, 0, 0, 0, 0,0,0,0,0,0,0,0,0,0,0,0,0,0,0,0},
  { 0, 0, 1, 1, 0, 0, 0, 0, 0, 0,0,0,0,0,0,0,0,0,0,0,0,0,0,0,0}};
constexpr int MT_DX[9][25] = {
  {-2,-1,0,1,2,-2,-1,0,1,2,-2,-1,0,1,2,-2,-1,0,1,2,-2,-1,0,1,2},
  {-2,-1, 0,-2,-1, 0,-2,-1, 0, 0,0,0,0,0,0,0,0,0,0,0,0,0,0,0,0},
  {-1, 0,-1, 0,-1, 0, 0, 0, 0, 0,0,0,0,0,0,0,0,0,0,0,0,0,0,0,0},
  {-2,-1, 0,-2,-1, 0, 0, 0, 0, 0,0,0,0,0,0,0,0,0,0,0,0,0,0,0,0},
  {-1, 0,-1, 0, 0, 0, 0, 0, 0, 0,0,0,0,0,0,0,0,0,0,0,0,0,0,0,0},
  { 0, 1, 2, 0, 1, 2, 0, 1, 2, 0,0,0,0,0,0,0,0,0,0,0,0,0,0,0,0},
  { 0, 1, 0, 1, 0, 1, 0, 0, 0, 0,0,0,0,0,0,0,0,0,0,0,0,0,0,0,0},
  { 0, 1, 2, 0, 1, 2, 0, 0, 0, 0,0,0,0,0,0,0,0,0,0,0,0,0,0,0,0},
  { 0, 1, 0, 1, 0, 0, 0, 0, 0, 0,0,0,0,0,0,0,0,0,0,0,0,0,0,0,0}};
constexpr int MT_WI[9][25] = {
  {0,1,2,3,4,5,6,7,8,9,10,11,12,13,14,15,16,17,18,19,20,21,22,23,24},
  {0, 2, 4,10,12,14,20,22,24, 0,0,0,0,0,0,0,0,0,0,0,0,0,0,0,0},
  {1, 3,11,13,21,23, 0, 0, 0, 0,0,0,0,0,0,0,0,0,0,0,0,0,0,0,0},
  {5, 7, 9,15,17,19, 0, 0, 0, 0,0,0,0,0,0,0,0,0,0,0,0,0,0,0,0},
  {6, 8,16,18, 0, 0, 0, 0, 0, 0,0,0,0,0,0,0,0,0,0,0,0,0,0,0,0},
  {0, 2, 4,10,12,14,20,22,24, 0,0,0,0,0,0,0,0,0,0,0,0,0,0,0,0},
  {1, 3,11,13,21,23, 0, 0, 0, 0,0,0,0,0,0,0,0,0,0,0,0,0,0,0,0},
  {5, 7, 9,15,17,19, 0, 0, 0, 0,0,0,0,0,0,0,0,0,0,0,0,0,0,0,0},
  {6, 8,16,18, 0, 0, 0, 0, 0, 0,0,0,0,0,0,0,0,0,0,0,0,0,0,0,0}};

// ---- ONE-SHOT weight prep (unchanged from r13) -----------------------------
__global__ __launch_bounds__(256) void pack_all(
    const float* __restrict__ t1a_w, const float* __restrict__ t1b_w,
    const float* __restrict__ t3b_w, const float* __restrict__ t2b_w,
    const float* __restrict__ t3a_w, const float* __restrict__ t2a_w,
    const float* __restrict__ c2a_w, const float* __restrict__ c3a_w,
    const float* __restrict__ c1b_w, const float* __restrict__ c2b_w,
    const float* __restrict__ c3b_w,
    float* __restrict__ wf, unsigned short* __restrict__ wpkb)
{
    constexpr int NJ = 26;
    constexpr int blk0[NJ + 1] =
        {0, 7, 8, 1608, 2008, 2296, 2488, 2680, 2808, 3096, 3288, 3480, 3608,
         4408, 5208, 5352, 5448, 5544, 5608, 6184, 6568, 6952, 7208,
         7352, 7448, 7544, 7608};
    constexpr int jkind[NJ] = {0,0,1,1,1,1,1,1,1,1,1,1,2,2, 2,2,2,2, 2,2,2,2, 2,2,2,2};
    constexpr int jmode[NJ] = {0,0,0,0,1,2,3,4,1,2,3,4,0,0, 5,6,7,8, 5,6,7,8, 5,6,7,8};
    constexpr int jci[NJ]   = {64,1,128,64,64,64,64,64,128,128,128,128,64,128,
                               64,64,64,64, 128,128,128,128, 64,64,64,64};
    constexpr int jco[NJ]   = {1,1,128,64,128,128,128,128,64,64,64,64,128,64,
                               64,64,64,64, 128,128,128,128, 64,64,64,64};
    constexpr int jsrc[NJ]  = {0,1,2,3,4,4,4,4,5,5,5,5,6,7, 8,8,8,8, 9,9,9,9, 10,10,10,10};
    constexpr long long jdst[NJ] = {921600,923200, 0,819200,
        1024000,1171456,1269760,1368064, 1433600,1581056,1679360,1777664,
        1843200, 2252800,
        2662400, 2736128, 2785280, 2834432,
        2867200, 3162112, 3358720, 3555328,
        3686400, 3760128, 3809280, 3858432};

    int b = blockIdx.x, j = 0;
#pragma unroll
    for (int k = 0; k < NJ; ++k) if (b >= blk0[k + 1]) j = k + 1;
    if (j >= NJ) return;
    const float* srcs[11] = {t1a_w, t1b_w, t3b_w, t2b_w, t3a_w, t2a_w,
                             c2a_w, c3a_w, c1b_w, c2b_w, c3b_w};
    const float* src = srcs[jsrc[j]];
    int idx = (b - blk0[j]) * 256 + (int)threadIdx.x;
    const int Ci = jci[j], Co = jco[j], mode = jmode[j];

    if (jkind[j] == 0) {
        int n = Ci * Co * 25;
        if (idx >= n) return;
        int t = idx % 25, rest = idx / 25;
        int ci = rest % Ci, co = rest / Ci;
        wf[jdst[j] + idx] = src[((size_t)ci * Co + co) * 25 + (24 - t)];
    } else {
        int NT = MT_N[mode];
        int nCB = Ci >> 5, nCoF = Co >> 4;
        int total = NT * nCB * nCoF * 512;
        if (idx >= total) return;
        int jj = idx & 7, lane = (idx >> 3) & 63;
        int rest = idx >> 9;
        int cof = rest % nCoF; int rest2 = rest / nCoF;
        int cb = rest2 % nCB;  int t = rest2 / nCB;
        int co = cof * 16 + (lane & 15);
        int ci = (cb << 5) + (lane >> 4) * 8 + jj;
        int wi = MT_WI[mode][t];
        float v = (jkind[j] == 1)
            ? src[((size_t)ci * Co + co) * 25 + (24 - wi)]   // flipped convT
            : src[((size_t)co * Ci + ci) * 25 + wi];         // direct conv
        _Float16 h = (_Float16)v;
        _Float16 l = (_Float16)(v - (float)h);
        unsigned short* dst = wpkb + jdst[j];
        size_t base = (size_t)rest * 1024;
        dst[base + lane * 8 + jj] = __builtin_bit_cast(unsigned short, h);
        dst[base + 512 + lane * 8 + jj] = __builtin_bit_cast(unsigned short, l);
    }
}

// LDS pixel stride: 2-limb needs 128B payload (+16 pad); single-limb 64 (+16).
template<int NPROD> struct lds_stride { static constexpr int v = 144; };
template<> struct lds_stride<1>       { static constexpr int v = 80;  };

// ---- tap compute (verified MFMA inner loop, fp16; NPROD 3=2-limb, 1=single)
template<int MODE, int CO_F, int NPROD>
__device__ __forceinline__ void mfma_taps(
    const char* s_x, const unsigned short* __restrict__ wpk,
    f32x4 (&acc)[4][CO_F], int lane, int wv, int px, int g,
    int cb, int nCB, int nCoF, int cof0)
{
    constexpr int NT = MT_N[MODE];
    constexpr int ST = lds_stride<NPROD>::v;
#pragma unroll
    for (int t = 0; t < NT; ++t) {
        const int dy = MT_DY[MODE][t], dx = MT_DX[MODE][t];
        f16x8 Bh[4], Bl[4];
#pragma unroll
        for (int rr = 0; rr < 4; ++rr) {
            int a = wv * 4 + rr;
            const char* p = &s_x[((a + dy + 2) * 20 + (dx + 2) + px) * ST + g * 16];
            Bh[rr] = *(const f16x8*)p;
            if constexpr (NPROD == 3) Bl[rr] = *(const f16x8*)(p + 64);
        }
#pragma unroll
        for (int cf = 0; cf < CO_F; ++cf) {
            const unsigned short* wp =
                wpk + ((size_t)(t * nCB + cb) * nCoF + (cof0 + cf)) * 1024 + (size_t)lane * 8;
            f16x8 Ah = *(const f16x8*)wp;
            if constexpr (NPROD == 3) {
                f16x8 Al = *(const f16x8*)(wp + 512);
#pragma unroll
                for (int rr = 0; rr < 4; ++rr) {
                    acc[rr][cf] = mfma16(Ah, Bh[rr], acc[rr][cf]);
                    acc[rr][cf] = mfma16(Ah, Bl[rr], acc[rr][cf]);
                    acc[rr][cf] = mfma16(Al, Bh[rr], acc[rr][cf]);
                }
            } else {
#pragma unroll
                for (int rr = 0; rr < 4; ++rr)
                    acc[rr][cf] = mfma16(Ah, Bh[rr], acc[rr][cf]);
            }
        }
    }
}

// staging: tile (ry,rx) -> orig (SS*(y0+ry-2)+sy, SS*(x0+rx-2)+sx); SS=1 or 2
template<int NPROD>
__device__ __forceinline__ void stage_tile(
    char* s_x, const float* __restrict__ inc, int tid,
    int y0, int x0, int SS, int sy, int sx, int Hin, int Win)
{
    constexpr int ST = lds_stride<NPROD>::v;
    for (int i = tid; i < 6400; i += 256) {
        int c2 = i / 400;
        int rem = i - c2 * 400;
        int ry = rem / 20, rx = rem - ry * 20;
        int y = SS * (y0 + ry - 2) + sy, x = SS * (x0 + rx - 2) + sx;
        float v0 = 0.f, v1 = 0.f;
        if ((unsigned)y < (unsigned)Hin && (unsigned)x < (unsigned)Win) {
            const float* p = inc + ((size_t)(c2 * 2) * Hin + y) * Win + x;
            v0 = p[0];
            v1 = p[(size_t)Hin * Win];
        }
        _Float16 h0 = (_Float16)v0, h1 = (_Float16)v1;
        char* base = &s_x[rem * ST + c2 * 4];
        *(unsigned*)(base) = (unsigned)__builtin_bit_cast(unsigned short, h0)
                           | ((unsigned)__builtin_bit_cast(unsigned short, h1) << 16);
        if constexpr (NPROD == 3) {
            _Float16 l0 = (_Float16)(v0 - (float)h0);
            _Float16 l1 = (_Float16)(v1 - (float)h1);
            *(unsigned*)(base + 64) = (unsigned)__builtin_bit_cast(unsigned short, l0)
                                    | ((unsigned)__builtin_bit_cast(unsigned short, l1) << 16);
        }
    }
}

// ---- stride-2 5x5 conv via 4-parity subplane MFMA (fp16 2-limb, encoder) ---
template<int CO_F>
__global__ __launch_bounds__(256) void conv_mfma_s2(
    const float* __restrict__ in,
    const unsigned short* __restrict__ w5, const unsigned short* __restrict__ w6,
    const unsigned short* __restrict__ w7, const unsigned short* __restrict__ w8,
    const float* __restrict__ bias, float* __restrict__ out,
    int Ci, int Co, int Hin, int Win, int Hout, int Wout, int nTX)
{
    __shared__ __align__(16) char s_x[400 * 144];
    const int tid = threadIdx.x;
    const int lane = tid & 63;
    const int wv = tid >> 6;
    const int px = lane & 15, g = lane >> 4;
    const int z = blockIdx.z;
    const int y0 = ((int)blockIdx.x / nTX) * 16;
    const int x0 = ((int)blockIdx.x % nTX) * 16;
    const int nCB = Ci >> 5;
    const int nCoF = Co >> 4;
    const int cof0 = (int)blockIdx.y * CO_F;
    const float* inz = in + (size_t)z * Ci * Hin * Win;

    f32x4 acc[4][CO_F];
#pragma unroll
    for (int rr = 0; rr < 4; ++rr)
#pragma unroll
        for (int cf = 0; cf < CO_F; ++cf) acc[rr][cf] = (f32x4){0.f, 0.f, 0.f, 0.f};

    for (int cb = 0; cb < nCB; ++cb) {
        const float* inc = inz + ((size_t)cb << 5) * Hin * Win;
        stage_tile<3>(s_x, inc, tid, y0, x0, 2, 0, 0, Hin, Win);
        __syncthreads();
        mfma_taps<5, CO_F, 3>(s_x, w5, acc, lane, wv, px, g, cb, nCB, nCoF, cof0);
        __syncthreads();
        stage_tile<3>(s_x, inc, tid, y0, x0, 2, 0, 1, Hin, Win);
        __syncthreads();
        mfma_taps<6, CO_F, 3>(s_x, w6, acc, lane, wv, px, g, cb, nCB, nCoF, cof0);
        __syncthreads();
        stage_tile<3>(s_x, inc, tid, y0, x0, 2, 1, 0, Hin, Win);
        __syncthreads();
        mfma_taps<7, CO_F, 3>(s_x, w7, acc, lane, wv, px, g, cb, nCB, nCoF, cof0);
        __syncthreads();
        stage_tile<3>(s_x, inc, tid, y0, x0, 2, 1, 1, Hin, Win);
        __syncthreads();
        mfma_taps<8, CO_F, 3>(s_x, w8, acc, lane, wv, px, g, cb, nCB, nCoF, cof0);
        __syncthreads();
    }
    const int ox = x0 + px;
    if (ox < Wout) {
#pragma unroll
        for (int rr = 0; rr < 4; ++rr) {
            int oy = y0 + wv * 4 + rr;
            if (oy < Hout) {
#pragma unroll
                for (int cf = 0; cf < CO_F; ++cf) {
                    int co = (cof0 + cf) * 16 + g * 4;
                    float* op = out + (((size_t)z * Co + co) * Hout + oy) * Wout + ox;
#pragma unroll
                    for (int i2 = 0; i2 < 4; ++i2) {
                        float v = acc[rr][cf][i2] + bias[co + i2];
                        op[(size_t)i2 * Hout * Wout] = v > 0.f ? v : 0.f;
                    }
                }
            }
        }
    }
}

// ---- MFMA conv body (s1 conv / convT parity; fp16, NPROD-templated) --------
template<int MODE, int CO_F, int NPROD>
__device__ __forceinline__ void conv_mfma_body(
    char* s_x,
    const float* __restrict__ in, const unsigned short* __restrict__ wpk,
    const float* __restrict__ bias, float* __restrict__ out,
    int Ci, int Co, int Hin, int Win, int Hout, int Wout,
    int nTX, int OS, int soy, int sox, int cofBlk)
{
    const int tid = threadIdx.x;
    const int lane = tid & 63;
    const int wv = tid >> 6;
    const int px = lane & 15, g = lane >> 4;
    const int z = blockIdx.z;
    const int y0 = ((int)blockIdx.x / nTX) * 16;
    const int x0 = ((int)blockIdx.x % nTX) * 16;
    const int nCB = Ci >> 5;
    const int nCoF = Co >> 4;
    const int cof0 = cofBlk * CO_F;
    const float* inz = in + (size_t)z * Ci * Hin * Win;

    f32x4 acc[4][CO_F];
#pragma unroll
    for (int rr = 0; rr < 4; ++rr)
#pragma unroll
        for (int cf = 0; cf < CO_F; ++cf) acc[rr][cf] = (f32x4){0.f, 0.f, 0.f, 0.f};

    for (int cb = 0; cb < nCB; ++cb) {
        const float* inc = inz + ((size_t)cb << 5) * Hin * Win;
        stage_tile<NPROD>(s_x, inc, tid, y0, x0, 1, 0, 0, Hin, Win);
        __syncthreads();
        mfma_taps<MODE, CO_F, NPROD>(s_x, wpk, acc, lane, wv, px, g, cb, nCB, nCoF, cof0);
        __syncthreads();
    }
    const int ox = (x0 + px) * OS + sox;
    if (ox < Wout) {
#pragma unroll
        for (int rr = 0; rr < 4; ++rr) {
            int oy = (y0 + wv * 4 + rr) * OS + soy;
            if (oy < Hout) {
#pragma unroll
                for (int cf = 0; cf < CO_F; ++cf) {
                    int co = (cof0 + cf) * 16 + g * 4;
                    float* op = out + (((size_t)z * Co + co) * Hout + oy) * Wout + ox;
#pragma unroll
                    for (int i2 = 0; i2 < 4; ++i2) {
                        float v = acc[rr][cf][i2] + bias[co + i2];
                        op[(size_t)i2 * Hout * Wout] = v > 0.f ? v : 0.f;
                    }
                }
            }
        }
    }
}

// s1-conv launches (mode 0)
template<int MODE, int CO_F, int NPROD = 3>
__global__ __launch_bounds__(256) void conv_mfma(
    const float* __restrict__ in, const unsigned short* __restrict__ wpk,
    const float* __restrict__ bias, float* __restrict__ out,
    int Ci, int Co, int Hin, int Win, int Hout, int Wout,
    int nTX, int OS, int soy, int sox)
{
    __shared__ __align__(16) char s_x[400 * lds_stride<NPROD>::v];
    conv_mfma_body<MODE, CO_F, NPROD>(s_x, in, wpk, bias, out, Ci, Co, Hin, Win,
                                      Hout, Wout, nTX, OS, soy, sox, (int)blockIdx.y);
}

// merged 4-parity convT (decoder, fp16 single-product, 32KB LDS)
template<int CO_F>
__global__ __launch_bounds__(256) void convt_mfma_all(
    const float* __restrict__ in,
    const unsigned short* __restrict__ w1, const unsigned short* __restrict__ w2,
    const unsigned short* __restrict__ w3, const unsigned short* __restrict__ w4,
    const float* __restrict__ bias, float* __restrict__ out,
    int Ci, int Co, int Hin, int Win, int Hout, int Wout, int nTX, int cofN)
{
    __shared__ __align__(16) char s_x[400 * lds_stride<1>::v];
    int m = (int)blockIdx.y / cofN;
    int yy = (int)blockIdx.y % cofN;
    if (m == 0)
        conv_mfma_body<1, CO_F, 1>(s_x, in, w1, bias, out, Ci, Co, Hin, Win, Hout, Wout, nTX, 2, 0, 0, yy);
    else if (m == 1)
        conv_mfma_body<2, CO_F, 1>(s_x, in, w2, bias, out, Ci, Co, Hin, Win, Hout, Wout, nTX, 2, 0, 1, yy);
    else if (m == 2)
        conv_mfma_body<3, CO_F, 1>(s_x, in, w3, bias, out, Ci, Co, Hin, Win, Hout, Wout, nTX, 2, 1, 0, yy);
    else
        conv_mfma_body<4, CO_F, 1>(s_x, in, w4, bias, out, Ci, Co, Hin, Win, Hout, Wout, nTX, 2, 1, 1, yy);
}

// ---- c1a: 1->64 s1p2 on 256x256, all 64 co per block (proven) -------------
__global__ __launch_bounds__(256, 4) void conv_c1a(
    const float* __restrict__ in, const float* __restrict__ w,  // w (64,25)
    const float* __restrict__ bias, float* __restrict__ out)
{
    __shared__ float s_in[36 * 36];
    const int z = blockIdx.z;
    const float* inz = in + (size_t)z * 65536;
    float* outz = out + (size_t)z * 64 * 65536;
    const int ty0 = ((int)blockIdx.x >> 3) * 32;
    const int tx0 = ((int)blockIdx.x & 7) * 32;
    const int tid = threadIdx.x;
    const int r  = tid >> 3;
    const int c4 = (tid & 7) * 4;
    const int iy0 = ty0 - 2, ix0 = tx0 - 2;

    for (int i = tid; i < 36 * 36; i += 256) {
        int rr = i / 36, cc = i - rr * 36;
        int y = iy0 + rr, x = ix0 + cc;
        float v = 0.f;
        if ((unsigned)y < 256u && (unsigned)x < 256u) v = inz[y * 256 + x];
        s_in[i] = v;
    }
    __syncthreads();

    float win[5][8];
#pragma unroll
    for (int ky = 0; ky < 5; ++ky) {
        const float* rowp = &s_in[(r + ky) * 36 + c4];
        float4 a = *(const float4*)rowp;
        float4 b = *(const float4*)(rowp + 4);
        win[ky][0]=a.x; win[ky][1]=a.y; win[ky][2]=a.z; win[ky][3]=a.w;
        win[ky][4]=b.x; win[ky][5]=b.y; win[ky][6]=b.z; win[ky][7]=b.w;
    }

    float* obase = outz + (size_t)(ty0 + r) * 256 + tx0 + c4;
    for (int j0 = 0; j0 < 64; j0 += 8) {
#pragma unroll
        for (int j = 0; j < 8; ++j) {
            const int co = j0 + j;
            const float* wj = w + co * 25;
            float a0 = 0.f, a1 = 0.f, a2 = 0.f, a3 = 0.f;
#pragma unroll
            for (int ky = 0; ky < 5; ++ky)
#pragma unroll
                for (int kx = 0; kx < 5; ++kx) {
                    float wv = wj[ky * 5 + kx];
                    a0 = fmaf(win[ky][kx],     wv, a0);
                    a1 = fmaf(win[ky][kx + 1], wv, a1);
                    a2 = fmaf(win[ky][kx + 2], wv, a2);
                    a3 = fmaf(win[ky][kx + 3], wv, a3);
                }
            float bv = bias[co];
            float4 v;
            v.x = a0 + bv; v.y = a1 + bv; v.z = a2 + bv; v.w = a3 + bv;
            v.x = v.x > 0.f ? v.x : 0.f;  v.y = v.y > 0.f ? v.y : 0.f;
            v.z = v.z > 0.f ? v.z : 0.f;  v.w = v.w > 0.f ? v.w : 0.f;
            *(float4*)(obase + (size_t)co * 65536) = v;
        }
    }
}

// ---- stride-1 5x5 conv (fp32), proven body (recon only) -------------------
template<int CO_PER>
__global__ __launch_bounds__(256) void conv5x5_s1(
    const float* __restrict__ in, const float* __restrict__ w,   // w (Co,Ci,25)
    const float* __restrict__ bias, float* __restrict__ out,
    int Ci, int Co, int Hin, int Win, int Hout, int Wout, int nTX)
{
    __shared__ float s_in[2][36 * 36];
    const int z = blockIdx.z;
    const float* inz = in + (size_t)z * Ci * Hin * Win;
    float* outz = out + (size_t)z * Co * Hout * Wout;
    const int co0 = blockIdx.y * CO_PER;
    const int ty0 = ((int)blockIdx.x / nTX) * 32;
    const int tx0 = ((int)blockIdx.x % nTX) * 32;
    const int tid = threadIdx.x;
    const int r  = tid >> 3;
    const int c4 = (tid & 7) * 4;
    const int oy = ty0 + r;
    const int ox0 = tx0 + c4;
    const int iy0 = ty0 - 2, ix0 = tx0 - 2;

    float acc[CO_PER][4];
#pragma unroll
    for (int j = 0; j < CO_PER; ++j)
#pragma unroll
        for (int p = 0; p < 4; ++p) acc[j][p] = 0.f;

    for (int ci0 = 0; ci0 < Ci; ci0 += 2) {
        const int nci = (Ci - ci0 >= 2) ? 2 : 1;
        for (int s = 0; s < nci; ++s) {
            const float* inc = inz + (size_t)(ci0 + s) * Hin * Win;
            for (int i = tid; i < 36 * 36; i += 256) {
                int rr = i / 36, cc = i - rr * 36;
                int y = iy0 + rr, x = ix0 + cc;
                float v = 0.f;
                if ((unsigned)y < (unsigned)Hin && (unsigned)x < (unsigned)Win)
                    v = inc[y * Win + x];
                s_in[s][i] = v;
            }
        }
        __syncthreads();
        for (int s = 0; s < nci; ++s) {
            const float* wc = w + (co0 * Ci + ci0 + s) * 25;
            float win[5][8];
#pragma unroll
            for (int ky = 0; ky < 5; ++ky) {
                const float* rowp = &s_in[s][(r + ky) * 36 + c4];
                float4 a = *(const float4*)rowp;
                float4 b = *(const float4*)(rowp + 4);
                win[ky][0]=a.x; win[ky][1]=a.y; win[ky][2]=a.z; win[ky][3]=a.w;
                win[ky][4]=b.x; win[ky][5]=b.y; win[ky][6]=b.z; win[ky][7]=b.w;
            }
#pragma unroll
            for (int j = 0; j < CO_PER; ++j) {
#pragma unroll
                for (int ky = 0; ky < 5; ++ky) {
#pragma unroll
                    for (int kx = 0; kx < 5; ++kx) {
                        float wv = wc[j * Ci * 25 + ky * 5 + kx];
#pragma unroll
                        for (int p = 0; p < 4; ++p)
                            acc[j][p] = fmaf(win[ky][p + kx], wv, acc[j][p]);
                    }
                }
            }
        }
        __syncthreads();
    }
    if (oy < Hout) {
#pragma unroll
        for (int j = 0; j < CO_PER; ++j) {
            const int co = co0 + j;
            const float bv = bias[co];
            float* orow = outz + (size_t)co * Hout * Wout + (size_t)oy * Wout;
#pragma unroll
            for (int p = 0; p < 4; ++p) {
                int ox = ox0 + p;
                if (ox < Wout) {
                    float v = acc[j][p] + bv;
                    orow[ox] = v > 0.f ? v : 0.f;
                }
            }
        }
    }
}

// ---- ConvTranspose2d stride=2 quad gather (fp32; t1a only) ----------------
template<int CO_PER>
__global__ __launch_bounds__(256) void convt5x5_quad(
    const float* __restrict__ in, const float* __restrict__ w,  // flipped (Co,Ci,25)
    const float* __restrict__ bias, float* __restrict__ out,
    int Ci, int Co, int Hin, int Win, int Hout, int Wout, int nTX)
{
    __shared__ float s_in[2][18 * 20];
    const int z = blockIdx.z;
    const float* inz = in + (size_t)z * Ci * Hin * Win;
    float* outz = out + (size_t)z * Co * Hout * Wout;
    const int co0 = blockIdx.y * CO_PER;
    const int a0 = ((int)blockIdx.x / nTX) * 16;
    const int b0 = ((int)blockIdx.x % nTX) * 16;
    const int tid = threadIdx.x;
    const int r = tid >> 4, c = tid & 15;

    float acc[CO_PER][4];
#pragma unroll
    for (int j = 0; j < CO_PER; ++j)
#pragma unroll
        for (int p = 0; p < 4; ++p) acc[j][p] = 0.f;

    for (int ci0 = 0; ci0 < Ci; ci0 += 2) {
        const int nci = (Ci - ci0 >= 2) ? 2 : 1;
        for (int s = 0; s < nci; ++s) {
            const float* inc = inz + (size_t)(ci0 + s) * Hin * Win;
            for (int i = tid; i < 18 * 18; i += 256) {
                int rr = i / 18, cc = i - rr * 18;
                int y = a0 - 2 + rr, x = b0 - 2 + cc;
                float v = 0.f;
                if (y >= 0 && y < Hin && x >= 0 && x < Win) v = inc[y * Win + x];
                s_in[s][rr * 20 + cc] = v;
            }
        }
        __syncthreads();
        for (int s = 0; s < nci; ++s) {
            const float* wc = w + (co0 * Ci + ci0 + s) * 25;
            float v[3][3];
#pragma unroll
            for (int i = 0; i < 3; ++i)
#pragma unroll
                for (int jx = 0; jx < 3; ++jx)
                    v[i][jx] = s_in[s][(r + i) * 20 + c + jx];
#pragma unroll
            for (int j = 0; j < CO_PER; ++j) {
                const float* wj = wc + j * Ci * 25;
#pragma unroll
                for (int ty = 0; ty < 3; ++ty)
#pragma unroll
                    for (int tx = 0; tx < 3; ++tx)
                        acc[j][0] = fmaf(v[ty][tx], wj[2*ty*5 + 2*tx], acc[j][0]);
#pragma unroll
                for (int ty = 0; ty < 3; ++ty)
#pragma unroll
                    for (int tx = 0; tx < 2; ++tx)
                        acc[j][1] = fmaf(v[ty][tx+1], wj[2*ty*5 + 2*tx+1], acc[j][1]);
#pragma unroll
                for (int ty = 0; ty < 2; ++ty)
#pragma unroll
                    for (int tx = 0; tx < 3; ++tx)
                        acc[j][2] = fmaf(v[ty+1][tx], wj[(2*ty+1)*5 + 2*tx], acc[j][2]);
#pragma unroll
                for (int ty = 0; ty < 2; ++ty)
#pragma unroll
                    for (int tx = 0; tx < 2; ++tx)
                        acc[j][3] = fmaf(v[ty+1][tx+1], wj[(2*ty+1)*5 + 2*tx+1], acc[j][3]);
            }
        }
        __syncthreads();
    }
    const int a = a0 + r, bq = b0 + c;
#pragma unroll
    for (int j = 0; j < CO_PER; ++j) {
        const int co = co0 + j;
        const float bv = bias[co];
        float* oc = outz + (size_t)co * Hout * Wout;
#pragma unroll
        for (int sy = 0; sy < 2; ++sy) {
            int oy = 2 * a + sy;
            if (oy < Hout) {
#pragma unroll
                for (int sx = 0; sx < 2; ++sx) {
                    int ox = 2 * bq + sx;
                    if (ox < Wout) {
                        float vv = acc[j][sy * 2 + sx] + bv;
                        oc[(size_t)oy * Wout + ox] = vv > 0.f ? vv : 0.f;
                    }
                }
            }
        }
    }
}

// VQ: argmin_k( ||e_k||^2 - 2 z.e_k ), float4 over k; strict < == first-min.
__global__ __launch_bounds__(256, 4) void vq_kernel(
    const float* __restrict__ before, const float* __restrict__ e,
    float* __restrict__ idxs_out, float* __restrict__ after,
    int npos, int HW)
{
    __shared__ float s_e[64 * 128];
    __shared__ float s_n[128];
    for (int i = threadIdx.x; i < 64 * 128; i += 256) s_e[i] = e[i];
    __syncthreads();
    if (threadIdx.x < 128) {
        int k = threadIdx.x;
        float s = 0.f;
#pragma unroll
        for (int d = 0; d < 64; ++d) { float v = s_e[d * 128 + k]; s += v * v; }
        s_n[k] = s;
    }
    __syncthreads();

    int p = blockIdx.x * 256 + threadIdx.x;
    if (p >= npos) return;
    int b = p / HW, r = p - b * HW;

    float zv[64];
#pragma unroll
    for (int d = 0; d < 64; ++d)
        zv[d] = before[((size_t)b * 64 + d) * HW + r];

    float best = 1e30f;
    int bi = 0;
    for (int k0 = 0; k0 < 128; k0 += 4) {
        float d0 = 0.f, d1 = 0.f, d2 = 0.f, d3 = 0.f;
#pragma unroll
        for (int d = 0; d < 64; ++d) {
            float4 ev = *(const float4*)&s_e[d * 128 + k0];
            d0 = fmaf(zv[d], ev.x, d0);
            d1 = fmaf(zv[d], ev.y, d1);
            d2 = fmaf(zv[d], ev.z, d2);
            d3 = fmaf(zv[d], ev.w, d3);
        }
        float m0 = s_n[k0]     - 2.f * d0;
        float m1 = s_n[k0 + 1] - 2.f * d1;
        float m2 = s_n[k0 + 2] - 2.f * d2;
        float m3 = s_n[k0 + 3] - 2.f * d3;
        if (m0 < best) { best = m0; bi = k0; }
        if (m1 < best) { best = m1; bi = k0 + 1; }
        if (m2 < best) { best = m2; bi = k0 + 2; }
        if (m3 < best) { best = m3; bi = k0 + 3; }
    }
    idxs_out[p] = (float)bi;
#pragma unroll
    for (int d = 0; d < 64; ++d)
        after[((size_t)b * 64 + d) * HW + r] = s_e[d * 128 + bi];
}

extern "C" void kernel_launch(void* const* d_in, const int* in_sizes, int n_in,
                              void* d_out, int out_size, void* d_ws, size_t ws_size,
                              hipStream_t stream)
{
    const float* x     = (const float*)d_in[0];
    const float* e     = (const float*)d_in[1];
    const float* c1a_w = (const float*)d_in[2];  const float* c1a_b = (const float*)d_in[3];
    const float* c1b_w = (const float*)d_in[4];  const float* c1b_b = (const float*)d_in[5];
    const float* c2a_w = (const float*)d_in[6];  const float* c2a_b = (const float*)d_in[7];
    const float* c2b_w = (const float*)d_in[8];  const float* c2b_b = (const float*)d_in[9];
    const float* c3a_w = (const float*)d_in[10]; const float* c3a_b = (const float*)d_in[11];
    const float* c3b_w = (const float*)d_in[12]; const float* c3b_b = (const float*)d_in[13];
    const float* t3a_w = (const float*)d_in[14]; const float* t3a_b = (const float*)d_in[15];
    const float* t3b_w = (const float*)d_in[16]; const float* t3b_b = (const float*)d_in[17];
    const float* t2a_w = (const float*)d_in[18]; const float* t2a_b = (const float*)d_in[19];
    const float* t2b_w = (const float*)d_in[20]; const float* t2b_b = (const float*)d_in[21];
    const float* t1a_w = (const float*)d_in[22]; const float* t1a_b = (const float*)d_in[23];
    const float* t1b_w = (const float*)d_in[24]; const float* t1b_b = (const float*)d_in[25];

    float* out = (float*)d_out;
    float* ws  = (float*)d_ws;

    // d_out layout: recon | idxs | before | after
    float* o_recon  = out;                // 16*253*253 = 1,024,144
    float* o_idxs   = out + 1024144;     // 16*29*29   = 13,456
    float* o_before = out + 1037600;     // 16*64*29*29= 861,184
    float* o_after  = out + 1898784;     // 861,184

    // --- exact tensor sizes (floats) ---
    constexpr size_t S_H1F  = (size_t)16 * 64 * 256 * 256;   // 67,108,864
    constexpr size_t S_H1G  = (size_t)8  * 64 * 256 * 256;   // 33,554,432
    constexpr size_t S126x64  = (size_t)16 * 64  * 126 * 126; // 16,257,024
    constexpr size_t S126x128 = (size_t)16 * 128 * 126 * 126; // 32,514,048
    constexpr size_t S61x128  = (size_t)16 * 128 * 61 * 61;   // 7,620,608
    constexpr size_t S61x64   = (size_t)16 * 64  * 61 * 61;   // 3,810,304
    constexpr size_t S125x64  = (size_t)16 * 64  * 125 * 125; // 16,000,000
    constexpr size_t S253     = (size_t)16 * 253 * 253;       // 1,024,144
    constexpr size_t S_WF     = 923232;    // flipped t1a/t1b weights region
    constexpr size_t S_WPK    = 1945600;   // MFMA packs: 3,891,200 ushorts

    // ---- full-batch plan ----
    constexpr size_t F_h1 = 0;
    constexpr size_t F_h2 = F_h1 + S_H1F;            // 67,108,864
    constexpr size_t F_h3 = 0;
    constexpr size_t F_h4 = F_h3 + S126x128;         // 32,514,048
    constexpr size_t F_h5 = F_h4 + S61x128;          // 40,134,656
    constexpr size_t F_wf = F_h2 + S126x64;          // 83,365,888
    constexpr size_t F_wk = F_wf + S_WF;             // 84,289,120
    constexpr size_t F_r1 = F_h5 + S61x64;           // 43,944,960
    constexpr size_t F_r2 = F_r1 + S61x128;          // 51,565,568
    constexpr size_t F_r3 = 0;
    constexpr size_t F_r4 = F_r3 + S125x64;          // 16,000,000
    constexpr size_t F_r5 = F_r2 + S61x128;          // 59,186,176
    constexpr size_t FULL_NEED = F_wk + S_WPK;       // 86,234,720

    // ---- 8-image-group fallback plan (the plan actually in use) ----
    constexpr size_t G_h1 = 0;
    constexpr size_t G_h2 = G_h1 + S_H1G;            // 33,554,432
    constexpr size_t G_h3 = 0;
    constexpr size_t G_h4 = G_h2;                    // overwrites dead h2
    constexpr size_t G_h5 = G_h4 + S61x128;          // 41,175,040
    constexpr size_t G_wf = G_h2 + S126x64;          // 49,811,456
    constexpr size_t G_wk = G_wf + S_WF;             // 50,734,688
    constexpr size_t G_r1 = 0;
    constexpr size_t G_r2 = G_r1 + S61x128;          // 7,620,608
    constexpr size_t G_r3 = G_r2 + S61x128;          // 15,241,216
    constexpr size_t G_r4 = G_r3 + S125x64;          // 31,241,216
    constexpr size_t G_r5 = G_r4 + S125x64;          // 47,241,216
    constexpr size_t G8_NEED = G_wk + S_WPK;         // 52,680,288

    static_assert(F_r5 + S253 <= F_h2, "F r5 under h2");
    static_assert(G_r5 + S253 <= G_wf, "g8 r5/wf");
    static_assert(G_h5 + S61x64 <= G_wf, "g8 h5/wf");

    if (ws_size < G8_NEED * sizeof(float)) return;
    const bool full = ws_size >= FULL_NEED * sizeof(float);

    float *h1, *h2, *h3, *h4, *h5, *wf, *r1, *r2, *r3, *r4, *r5;
    unsigned short* wpkb;
    if (full) {
        h1 = ws + F_h1; h2 = ws + F_h2; h3 = ws + F_h3; h4 = ws + F_h4;
        h5 = ws + F_h5; wf = ws + F_wf; r1 = ws + F_r1; r2 = ws + F_r2;
        r3 = ws + F_r3; r4 = ws + F_r4; r5 = ws + F_r5;
        wpkb = (unsigned short*)(ws + F_wk);
    } else {
        h1 = ws + G_h1; h2 = ws + G_h2; h3 = ws + G_h3; h4 = ws + G_h4;
        h5 = ws + G_h5; wf = ws + G_wf; r1 = ws + G_r1; r2 = ws + G_r2;
        r3 = ws + G_r3; r4 = ws + G_r4; r5 = ws + G_r5;
        wpkb = (unsigned short*)(ws + G_wk);
    }
    float* wf_t1a = wf + 921600;     // 1*64*25 = 1,600
    float* wf_t1b = wf + 923200;     // 25
    unsigned short* wpk_t3b = wpkb;                 // 819,200
    unsigned short* wpk_t2b = wpkb + 819200;        // 204,800
    unsigned short* wpk_t3a[4] = {wpkb + 1024000, wpkb + 1171456, wpkb + 1269760, wpkb + 1368064};
    unsigned short* wpk_t2a[4] = {wpkb + 1433600, wpkb + 1581056, wpkb + 1679360, wpkb + 1777664};
    unsigned short* wpk_c2a = wpkb + 1843200;       // 409,600 (fp16 direct)
    unsigned short* wpk_c3a = wpkb + 2252800;       // 409,600 (fp16 direct)
    unsigned short* wpk_c1b[4] = {wpkb + 2662400, wpkb + 2736128, wpkb + 2785280, wpkb + 2834432};
    unsigned short* wpk_c2b[4] = {wpkb + 2867200, wpkb + 3162112, wpkb + 3358720, wpkb + 3555328};
    unsigned short* wpk_c3b[4] = {wpkb + 3686400, wpkb + 3760128, wpkb + 3809280, wpkb + 3858432};

    // --- weight prep: single fused launch ---
    pack_all<<<dim3(7608), 256, 0, stream>>>(
        t1a_w, t1b_w, t3b_w, t2b_w, t3a_w, t2a_w, c2a_w, c3a_w,
        c1b_w, c2b_w, c3b_w, wf, wpkb);

    // --- encoder (3-product fp16; idxs-exact path; r13 geometry) ---
    if (full) {
        conv_c1a<<<dim3(64, 1, 16), 256, 0, stream>>>(x, c1a_w, c1a_b, h1);
        conv_mfma_s2<4><<<dim3(64, 1, 16), 256, 0, stream>>>(
            h1, wpk_c1b[0], wpk_c1b[1], wpk_c1b[2], wpk_c1b[3],
            c1b_b, h2, 64, 64, 256, 256, 126, 126, 8);
    } else {
        for (int g = 0; g < 2; ++g) {
            conv_c1a<<<dim3(64, 1, 8), 256, 0, stream>>>(
                x + (size_t)g * 8 * 65536, c1a_w, c1a_b, h1);
            conv_mfma_s2<4><<<dim3(64, 1, 8), 256, 0, stream>>>(
                h1, wpk_c1b[0], wpk_c1b[1], wpk_c1b[2], wpk_c1b[3],
                c1b_b, h2 + (size_t)g * 8 * 64 * 126 * 126,
                64, 64, 256, 256, 126, 126, 8);
        }
    }
    conv_mfma<0, 4, 3><<<dim3(64, 2, 16), 256, 0, stream>>>(
        h2, wpk_c2a, c2a_b, h3, 64, 128, 126, 126, 126, 126, 8, 1, 0, 0);
    conv_mfma_s2<4><<<dim3(16, 2, 16), 256, 0, stream>>>(
        h3, wpk_c2b[0], wpk_c2b[1], wpk_c2b[2], wpk_c2b[3],
        c2b_b, h4, 128, 128, 126, 126, 61, 61, 4);
    conv_mfma<0, 2, 3><<<dim3(16, 2, 16), 256, 0, stream>>>(
        h4, wpk_c3a, c3a_b, h5, 128, 64, 61, 61, 61, 61, 4, 1, 0, 0);
    conv_mfma_s2<4><<<dim3(4, 1, 16), 256, 0, stream>>>(
        h5, wpk_c3b[0], wpk_c3b[1], wpk_c3b[2], wpk_c3b[3],
        c3b_b, o_before, 64, 64, 61, 61, 29, 29, 2);

    // --- VQ ---
    vq_kernel<<<dim3(53), 256, 0, stream>>>(o_before, e, o_idxs, o_after, 13456, 841);

    // --- decoder (single-product fp16, 32KB LDS); fp32 for t1a/t1b ---
    convt_mfma_all<4><<<dim3(4, 8, 16), 256, 0, stream>>>(
        o_after, wpk_t3a[0], wpk_t3a[1], wpk_t3a[2], wpk_t3a[3],
        t3a_b, r1, 64, 128, 29, 29, 61, 61, 2, 2);                    // t3a
    conv_mfma<0, 4, 1><<<dim3(16, 2, 16), 256, 0, stream>>>(
        r1, wpk_t3b, t3b_b, r2, 128, 128, 61, 61, 61, 61, 4, 1, 0, 0); // t3b
    convt_mfma_all<4><<<dim3(16, 4, 16), 256, 0, stream>>>(
        r2, wpk_t2a[0], wpk_t2a[1], wpk_t2a[2], wpk_t2a[3],
        t2a_b, r3, 128, 64, 61, 61, 125, 125, 4, 1);                   // t2a
    conv_mfma<0, 4, 1><<<dim3(64, 1, 16), 256, 0, stream>>>(
        r3, wpk_t2b, t2b_b, r4, 64, 64, 125, 125, 125, 125, 8, 1, 0, 0); // t2b
    convt5x5_quad<1><<<dim3(64, 1, 16), 256, 0, stream>>>(
        r4, wf_t1a, t1a_b, r5, 64, 1, 125, 125, 253, 253, 8);          // t1a
    conv5x5_s1<1><<<dim3(64, 1, 16), 256, 0, stream>>>(
        r5, wf_t1b, t1b_b, o_recon, 1, 1, 253, 253, 253, 253, 8);      // recon
}